// Round 16
// baseline (132.674 us; speedup 1.0000x reference)
//
#include <hip/hip_runtime.h>

typedef __attribute__((ext_vector_type(8))) short s8v;        // 8 x bf16 bits
typedef __attribute__((ext_vector_type(2))) float f32x2;
typedef __attribute__((ext_vector_type(4))) float f32x4;
typedef __attribute__((ext_vector_type(16))) float f32x16;
typedef __attribute__((ext_vector_type(4))) unsigned short u16x4;
typedef __attribute__((ext_vector_type(4))) unsigned int u32x4;
typedef __attribute__((ext_vector_type(4))) _Float16 h16x4;

#define SEQ 4096
#define DM  768
#define NH  12
#define HD  64
#define QSCL 0.18033688f   // (1/sqrt(64)) * log2(e), folded into Q at QKV epilogue
#define FOFF 8.0f          // fixed softmax offset (log2 domain): P = exp2(p - 8)
#define NUNITS 2304        // 12 heads x (16 heavy qt x 8 splits + 16 light qt x 4)

__device__ __forceinline__ unsigned short f2bf(float f) {
  union { float f; unsigned int u; } v; v.f = f;
  unsigned int r = v.u + 0x7fffu + ((v.u >> 16) & 1u);
  return (unsigned short)(r >> 16);
}

__device__ __forceinline__ unsigned int cvtpk(float lo, float hi) {
  unsigned int r;
  asm("v_cvt_pk_bf16_f32 %0, %1, %2" : "=v"(r) : "v"(lo), "v"(hi));
  return r;
}

__device__ __forceinline__ void gload16(const void* g, void* l) {
  __builtin_amdgcn_global_load_lds((const __attribute__((address_space(1))) void*)g,
                                   (__attribute__((address_space(3))) void*)l, 16, 0, 0);
}

// ---------------- fused prep: cast tokens + transpose-cast both weights ----------------
// blocks [0,3072): cast tokens; [3072,4800): transpose wqkv; [4800,5376): transpose wproj
__global__ __launch_bounds__(256) void k_prep(
    const float* __restrict__ tokens, const float* __restrict__ wqkv,
    const float* __restrict__ wproj, unsigned short* __restrict__ tok,
    unsigned short* __restrict__ wqkvT, unsigned short* __restrict__ wprojT) {
  __shared__ float tile[32][33];
  const int b = blockIdx.x;
  const int tid = threadIdx.x;
  if (b < 3072) {
    int i = (b * 256 + tid) * 4;
    float4 v = *reinterpret_cast<const float4*>(tokens + i);
    u16x4 o;
    o.x = f2bf(v.x); o.y = f2bf(v.y); o.z = f2bf(v.z); o.w = f2bf(v.w);
    *reinterpret_cast<u16x4*>(tok + i) = o;
    return;
  }
  const float* in;
  unsigned short* out;
  int idx, N;
  if (b < 4800) { idx = b - 3072; in = wqkv;  out = wqkvT;  N = 2304; }
  else          { idx = b - 4800; in = wproj; out = wprojT; N = 768;  }
  const int k0 = (idx % 24) * 32, n0 = (idx / 24) * 32;
  const int tr = tid >> 5, tc = tid & 31;
#pragma unroll
  for (int i = 0; i < 4; i++)
    tile[i * 8 + tr][tc] = in[(k0 + i * 8 + tr) * N + n0 + tc];
  __syncthreads();
#pragma unroll
  for (int i = 0; i < 4; i++)
    out[(n0 + i * 8 + tr) * 768 + k0 + tc] = f2bf(tile[tc][i * 8 + tr]);
}

// ---------------- 128x128 bf16 MFMA GEMM (round-10 proven form) ----------------
// A[M][768] @ BT[N][768]^T, single-buffered (rounds 11/14: explicit dbuf,
// launch-bound caps, XCD swizzle, fused-merge A-path all regressed).
// MODE 0: QKV epilogue -> Q (pre-scaled by QSCL) / K row-major bf16, V transposed
// MODE 1: fp32 output + bias
template<int MODE>
__global__ __launch_bounds__(256) void k_gemm(
    const unsigned short* __restrict__ A, const unsigned short* __restrict__ BT,
    const float* __restrict__ bias,
    unsigned short* __restrict__ Oq, unsigned short* __restrict__ Ok,
    unsigned short* __restrict__ Ov, float* __restrict__ Of) {
  __shared__ unsigned short As[128 * 32];
  __shared__ unsigned short Bs[128 * 32];
  const int tid = threadIdx.x;
  const int lane = tid & 63;
  const int w = tid >> 6;
  const int wm = w >> 1, wn = w & 1;
  const int l15 = lane & 15, l4 = lane >> 4;
  const int m0 = blockIdx.x * 128, n0 = blockIdx.y * 128;

  f32x4 acc[4][4] = {};

  int srow[2], skc[2];
#pragma unroll
  for (int j = 0; j < 2; j++) {
    int slot = j * 256 + tid;
    srow[j] = slot >> 2;
    skc[j] = (slot & 3) ^ ((srow[j] >> 1) & 3);
  }
  const int ldsb0 = (tid & ~63) * 16;
  const int ldsb1 = (256 + (tid & ~63)) * 16;

  for (int k0 = 0; k0 < DM; k0 += 32) {
    gload16(A + (m0 + srow[0]) * DM + k0 + skc[0] * 8, (char*)As + ldsb0);
    gload16(A + (m0 + srow[1]) * DM + k0 + skc[1] * 8, (char*)As + ldsb1);
    gload16(BT + (n0 + srow[0]) * DM + k0 + skc[0] * 8, (char*)Bs + ldsb0);
    gload16(BT + (n0 + srow[1]) * DM + k0 + skc[1] * 8, (char*)Bs + ldsb1);
    __syncthreads();
    s8v af[4], bfr[4];
#pragma unroll
    for (int i = 0; i < 4; i++) {
      int ra = wm * 64 + i * 16 + l15;
      int ca = (l4 ^ ((ra >> 1) & 3)) * 8;
      af[i] = *reinterpret_cast<const s8v*>(&As[ra * 32 + ca]);
      int rb = wn * 64 + i * 16 + l15;
      int cb = (l4 ^ ((rb >> 1) & 3)) * 8;
      bfr[i] = *reinterpret_cast<const s8v*>(&Bs[rb * 32 + cb]);
    }
#pragma unroll
    for (int mi = 0; mi < 4; mi++)
#pragma unroll
      for (int nj = 0; nj < 4; nj++)
        acc[mi][nj] = __builtin_amdgcn_mfma_f32_16x16x32_bf16(af[mi], bfr[nj], acc[mi][nj], 0, 0, 0);
    __syncthreads();
  }

#pragma unroll
  for (int nj = 0; nj < 4; nj++) {
    const int col = n0 + wn * 64 + nj * 16 + l15;
    const float bv = bias[col];
#pragma unroll
    for (int mi = 0; mi < 4; mi++) {
      const int rowb = m0 + wm * 64 + mi * 16 + l4 * 4;
      if (MODE == 0) {
        if (col < 768) {
#pragma unroll
          for (int r = 0; r < 4; r++)
            Oq[(rowb + r) * DM + col] = f2bf((acc[mi][nj][r] + bv) * QSCL);
        } else if (col < 1536) {
#pragma unroll
          for (int r = 0; r < 4; r++)
            Ok[(rowb + r) * DM + (col - 768)] = f2bf(acc[mi][nj][r] + bv);
        } else {
          u16x4 pk;
#pragma unroll
          for (int r = 0; r < 4; r++)
            pk[r] = f2bf(acc[mi][nj][r] + bv);
          *reinterpret_cast<u16x4*>(&Ov[(col - 1536) * SEQ + rowb]) = pk;
        }
      } else {
#pragma unroll
        for (int r = 0; r < 4; r++)
          Of[(rowb + r) * DM + col] = acc[mi][nj][r] + bv;
      }
    }
  }
}

// ---------------- causal flash attention: persistent blocks + dynamic work queue ----
// Grid 1280 = exactly 5 blocks/CU (LDS 32KB ceiling) -- residency stays 5 until
// the queue drains (round-15 lesson: sustained residency beats uniform cost).
// Unit u (pulled via plain atomicAdd, no fences -- units are independent):
//   heavy (u<1536): qt = 31-u/96 (>=16), 8-way key-split;
//   light: qt = 15-(u-1536)/48, 4-way split. All units <= 8 key-tiles.
// Inner pipeline = round-10 proven form: 4 waves x 32 q-rows, swapped QK^T
// (mfma32(K,Q)), fixed-offset softmax exp2(p-8) folded into MFMA C-init,
// in-register P->B-frag via cvt_pk + permlane32_swap, K/V LDS-staged 2-phase
// async global_load_lds pipeline. Partials (f16 O, f32 l) -> workspace.
__global__ __launch_bounds__(256, 4) void k_attn(
    const unsigned short* __restrict__ Qb, const unsigned short* __restrict__ Kb,
    const unsigned short* __restrict__ Vt, _Float16* __restrict__ Opart,
    float* __restrict__ lw, int* __restrict__ ctr) {
  __shared__ unsigned short Ks[2][64 * 64];   // [key][d], slot-swizzled, 8KB each
  __shared__ unsigned short Vs[2][64 * 64];   // [d][key], slot-swizzled, 8KB each
  __shared__ int su;
  const int tid = threadIdx.x;
  const int lane = tid & 63;
  const int w = tid >> 6;
  const int l31 = lane & 31, lh = lane >> 5;

  int srow[2], scol[2];
#pragma unroll
  for (int j = 0; j < 2; j++) {
    int c = j * 256 + tid;
    srow[j] = c >> 3;
    scol[j] = ((c & 7) ^ (srow[j] & 7)) * 8;
  }
  const int ldsoff0 = (tid & ~63) * 16;
  const int ldsoff1 = 4096 + (tid & ~63) * 16;
  const int x7 = l31 & 7;
  const int rbase = l31 * 128;

  while (true) {
    if (tid == 0) su = atomicAdd(ctr, 1);
    __syncthreads();
    const int u = su;
    if (u >= NUNITS) break;

    // ---- decode unit: heavy first (qt 31..16, 8-way), then light (15..0, 4-way)
    int qt, head, s, nsplit;
    if (u < 1536) {
      qt = 31 - u / 96;
      const int r = u % 96;
      head = r >> 3;
      s = r & 7;
      nsplit = 8;
    } else {
      const int v = u - 1536;
      qt = 15 - v / 48;
      const int r = v % 48;
      head = r >> 2;
      s = r & 3;
      nsplit = 4;
    }
    const int q0w = qt * 128 + w * 32;     // this wave's first q-row
    const int ntiles = 2 * qt + 2;
    const unsigned short* const Kh = Kb + head * HD;
    const unsigned short* const Vh = Vt + head * HD * SEQ;
    const int kstep = nsplit * 64 * DM;
    const int vstep = nsplit * 64;

    int koff0 = (s * 64 + srow[0]) * DM + scol[0];
    int koff1 = (s * 64 + srow[1]) * DM + scol[1];
    int voff0 = srow[0] * SEQ + s * 64 + scol[0];
    int voff1 = srow[1] * SEQ + s * 64 + scol[1];

    // Q frags (B-operand): lane holds q = q0w+l31, k-slice kc*16 + lh*8 .. +7
    s8v aq[4];
#pragma unroll
    for (int kc = 0; kc < 4; kc++)
      aq[kc] = *reinterpret_cast<const s8v*>(
          &Qb[(q0w + l31) * DM + head * HD + kc * 16 + lh * 8]);

    f32x16 O0 = {}, O1 = {};   // O^T[d][q]: d = db*32 + (r&3)+8*(r>>2)+4*lh, q = l31
    float lsum = 0.f;

    // ---- prologue: stage tile t=s into buffer 0 (if it exists) ----
    if (s < ntiles) {
      gload16(Kh + koff0, (char*)Ks[0] + ldsoff0);
      gload16(Kh + koff1, (char*)Ks[0] + ldsoff1);
      gload16(Vh + voff0, (char*)Vs[0] + ldsoff0);
      gload16(Vh + voff1, (char*)Vs[0] + ldsoff1);
      __asm__ volatile("s_waitcnt vmcnt(0)" ::: "memory");
    }
    __syncthreads();
    koff0 += kstep; koff1 += kstep;
    voff0 += vstep; voff1 += vstep;

    int cur = 0;
    for (int t = s; t < ntiles; t += nsplit) {
      // ---- stage tile t+nsplit (async, no VGPR cost) ----
      if (t + nsplit < ntiles) {
        const int nxt = cur ^ 1;
        gload16(Kh + koff0, (char*)Ks[nxt] + ldsoff0);
        gload16(Kh + koff1, (char*)Ks[nxt] + ldsoff1);
        gload16(Vh + voff0, (char*)Vs[nxt] + ldsoff0);
        gload16(Vh + voff1, (char*)Vs[nxt] + ldsoff1);
      }
      koff0 += kstep; koff1 += kstep;
      voff0 += vstep; voff1 += vstep;
      const int kb = t * 64;
      // wave-active check: fully-masked tiles (kb > q0w+31) skip compute.
      if (kb <= q0w + 31) {
        const char* const kbuf = (const char*)Ks[cur];
        const char* const vbuf = (const char*)Vs[cur];
        // ---- swapped QK^T: S^T[key][q]; C-init = -FOFF folds softmax offset ----
        f32x16 z0, z1;
#pragma unroll
        for (int r = 0; r < 16; r++) { z0[r] = -FOFF; z1[r] = -FOFF; }
        __builtin_amdgcn_s_setprio(1);
#pragma unroll
        for (int kc = 0; kc < 4; kc++) {
          const int so = ((kc * 2 + lh) ^ x7) << 4;
          const s8v k0 = *reinterpret_cast<const s8v*>(kbuf + rbase + so);
          const s8v k1 = *reinterpret_cast<const s8v*>(kbuf + 4096 + rbase + so);
          z0 = __builtin_amdgcn_mfma_f32_32x32x16_bf16(k0, aq[kc], z0, 0, 0, 0);
          z1 = __builtin_amdgcn_mfma_f32_32x32x16_bf16(k1, aq[kc], z1, 0, 0, 0);
        }
        __builtin_amdgcn_s_setprio(0);
        // causal mask: only diagonal tiles (wave-uniform branch)
        if (kb + 63 > q0w) {
          const int qm = q0w + l31 - kb - 4 * lh;   // mask if koff > qm
#pragma unroll
          for (int r = 0; r < 16; r++) {
            const int koff = (r & 3) + 8 * (r >> 2);
            z0[r] = (koff > qm) ? -1e30f : z0[r];
            z1[r] = (koff + 32 > qm) ? -1e30f : z1[r];
          }
        }
        // ---- exp (offset pre-folded) + paired row-sum (v_pk_add_f32) ----
        f32x2 sa = {0.f, 0.f}, sb = {0.f, 0.f};
#pragma unroll
        for (int r = 0; r < 8; r++) {
          z0[2 * r] = exp2f(z0[2 * r]);
          z0[2 * r + 1] = exp2f(z0[2 * r + 1]);
          f32x2 e0; e0[0] = z0[2 * r]; e0[1] = z0[2 * r + 1];
          sa += e0;
          z1[2 * r] = exp2f(z1[2 * r]);
          z1[2 * r + 1] = exp2f(z1[2 * r + 1]);
          f32x2 e1; e1[0] = z1[2 * r]; e1[1] = z1[2 * r + 1];
          sb += e1;
        }
        sa += sb;
        lsum += sa[0] + sa[1];
        // ---- P -> PV B-frags: 16 cvt_pk + 8 permlane32_swap (in-register) ----
        s8v pf[4];
#define PACKKC(V, base, dst)                                                 \
        {                                                                    \
          unsigned int A0 = cvtpk(V[base + 0], V[base + 1]);                 \
          unsigned int B0 = cvtpk(V[base + 2], V[base + 3]);                 \
          unsigned int A1 = cvtpk(V[base + 4], V[base + 5]);                 \
          unsigned int B1 = cvtpk(V[base + 6], V[base + 7]);                 \
          asm("v_permlane32_swap_b32 %0, %1" : "+v"(A0), "+v"(A1));          \
          asm("v_permlane32_swap_b32 %0, %1" : "+v"(B0), "+v"(B1));          \
          u32x4 q_ = {A0, B0, A1, B1};                                       \
          dst = __builtin_bit_cast(s8v, q_);                                 \
        }
        PACKKC(z0, 0, pf[0]);
        PACKKC(z0, 8, pf[1]);
        PACKKC(z1, 0, pf[2]);
        PACKKC(z1, 8, pf[3]);
#undef PACKKC
        // ---- swapped PV: O^T[d][q] += V^T x P ----
        __builtin_amdgcn_s_setprio(1);
#pragma unroll
        for (int kc = 0; kc < 4; kc++) {
          const int so = ((kc * 2 + lh) ^ x7) << 4;
          const s8v v0 = *reinterpret_cast<const s8v*>(vbuf + rbase + so);
          const s8v v1 = *reinterpret_cast<const s8v*>(vbuf + 4096 + rbase + so);
          O0 = __builtin_amdgcn_mfma_f32_32x32x16_bf16(v0, pf[kc], O0, 0, 0, 0);
          O1 = __builtin_amdgcn_mfma_f32_32x32x16_bf16(v1, pf[kc], O1, 0, 0, 0);
        }
        __builtin_amdgcn_s_setprio(0);
      }
      // ---- next tile staged & everyone done reading cur ----
      __asm__ volatile("s_waitcnt vmcnt(0)" ::: "memory");
      __syncthreads();
      cur ^= 1;
    }

    // ---- publish partials: f16 unnormalized O, f32 l per q-row ----
    lsum += __shfl_xor(lsum, 32);
    _Float16* const op = Opart + (size_t)s * SEQ * DM + (size_t)(q0w + l31) * DM +
                         head * HD + 4 * lh;
#pragma unroll
    for (int k = 0; k < 4; k++) {
      h16x4 o0h, o1h;
#pragma unroll
      for (int r = 0; r < 4; r++) {
        o0h[r] = (_Float16)O0[k * 4 + r];
        o1h[r] = (_Float16)O1[k * 4 + r];
      }
      *reinterpret_cast<h16x4*>(op + 8 * k) = o0h;        // d = 8k + 4lh + r
      *reinterpret_cast<h16x4*>(op + 32 + 8 * k) = o1h;   // d = 32 + 8k + 4lh + r
    }
    if (lh == 0)
      lw[(s * NH + head) * SEQ + q0w + l31] = lsum;
    __syncthreads();   // all waves done before next unit re-stages LDS
  }
}

// ---------------- merge key-split partials (plain sums) -> bf16 attn ----------------
// rows >= 2048 (heavy qt >= 16) have 8 partials; lighter rows have 4.
__global__ __launch_bounds__(256) void k_merge(const _Float16* __restrict__ Opart,
                                               const float* __restrict__ lw,
                                               unsigned short* __restrict__ attn) {
  const int idx = blockIdx.x * 256 + threadIdx.x;
  const int e4 = idx * 4;                   // 4 consecutive d-elements
  const int row = e4 / DM;
  const int col = e4 - row * DM;
  const int head = col >> 6;
  const size_t SD = (size_t)SEQ * DM;
  float l = 0.f;
  float acc[4] = {0.f, 0.f, 0.f, 0.f};
#pragma unroll
  for (int s = 0; s < 4; s++) {
    l += lw[(s * NH + head) * SEQ + row];
    const h16x4 o = *reinterpret_cast<const h16x4*>(Opart + s * SD + e4);
#pragma unroll
    for (int j = 0; j < 4; j++) acc[j] += (float)o[j];
  }
  if (row >= 2048) {
#pragma unroll
    for (int s = 4; s < 8; s++) {
      l += lw[(s * NH + head) * SEQ + row];
      const h16x4 o = *reinterpret_cast<const h16x4*>(Opart + s * SD + e4);
#pragma unroll
      for (int j = 0; j < 4; j++) acc[j] += (float)o[j];
    }
  }
  const float rl = 1.f / l;
  u16x4 pk;
#pragma unroll
  for (int j = 0; j < 4; j++) pk[j] = f2bf(acc[j] * rl);
  *reinterpret_cast<u16x4*>(attn + e4) = pk;
}

extern "C" void kernel_launch(void* const* d_in, const int* in_sizes, int n_in,
                              void* d_out, int out_size, void* d_ws, size_t ws_size,
                              hipStream_t stream) {
  (void)in_sizes; (void)n_in; (void)out_size; (void)ws_size;
  const float* tokens = (const float*)d_in[0];
  const float* wqkv  = (const float*)d_in[2];
  const float* bqkv  = (const float*)d_in[3];
  const float* wproj = (const float*)d_in[4];
  const float* bproj = (const float*)d_in[5];
  float* out = (float*)d_out;

  unsigned short* tok    = (unsigned short*)d_ws;       // [4096][768]; reused as attn
  unsigned short* wqkvT  = tok + 4096 * 768;            // [2304][768]
  unsigned short* wprojT = wqkvT + 2304 * 768;          // [768][768]
  unsigned short* Qb     = wprojT + 768 * 768;          // [4096][768] (pre-scaled)
  unsigned short* Kb     = Qb + 4096 * 768;             // [4096][768]
  unsigned short* Vt     = Kb + 4096 * 768;             // [768][4096]
  _Float16* Opart = (_Float16*)(Vt + 768 * 4096);       // 8 x [4096][768] f16
  float* lw = (float*)(Opart + 8 * (size_t)4096 * 768); // 8 x 12 x 4096 f32
  int* ctr = (int*)(lw + 8 * NH * SEQ);                 // work-queue counter
  unsigned short* attn = tok;                           // alias: tok dead after gemm0

  hipMemsetAsync(ctr, 0, sizeof(int), stream);
  k_prep<<<5376, 256, 0, stream>>>(tokens, wqkv, wproj, tok, wqkvT, wprojT);
  k_gemm<0><<<dim3(32, 18), 256, 0, stream>>>(tok, wqkvT, bqkv, Qb, Kb, Vt, nullptr);
  k_attn<<<1280, 256, 0, stream>>>(Qb, Kb, Vt, Opart, lw, ctr);
  k_merge<<<3072, 256, 0, stream>>>(Opart, lw, attn);
  k_gemm<1><<<dim3(32, 6), 256, 0, stream>>>(attn, wprojT, bproj, nullptr, nullptr, nullptr, out);
}

// Round 17
// 103.903 us; speedup vs baseline: 1.2769x; 1.2769x over previous
//
#include <hip/hip_runtime.h>

typedef __attribute__((ext_vector_type(8))) short s8v;        // 8 x bf16 bits
typedef __attribute__((ext_vector_type(2))) float f32x2;
typedef __attribute__((ext_vector_type(4))) float f32x4;
typedef __attribute__((ext_vector_type(16))) float f32x16;
typedef __attribute__((ext_vector_type(4))) unsigned short u16x4;
typedef __attribute__((ext_vector_type(4))) unsigned int u32x4;
typedef __attribute__((ext_vector_type(4))) _Float16 h16x4;

#define SEQ 4096
#define DM  768
#define NH  12
#define HD  64
#define QSCL 0.18033688f   // (1/sqrt(64)) * log2(e), folded into Q at QKV epilogue
#define FOFF 8.0f          // fixed softmax offset (log2 domain): P = exp2(p - 8)

__device__ __forceinline__ unsigned short f2bf(float f) {
  union { float f; unsigned int u; } v; v.f = f;
  unsigned int r = v.u + 0x7fffu + ((v.u >> 16) & 1u);
  return (unsigned short)(r >> 16);
}

__device__ __forceinline__ unsigned int cvtpk(float lo, float hi) {
  unsigned int r;
  asm("v_cvt_pk_bf16_f32 %0, %1, %2" : "=v"(r) : "v"(lo), "v"(hi));
  return r;
}

__device__ __forceinline__ void gload16(const void* g, void* l) {
  __builtin_amdgcn_global_load_lds((const __attribute__((address_space(1))) void*)g,
                                   (__attribute__((address_space(3))) void*)l, 16, 0, 0);
}

// ---------------- fused prep: cast tokens + transpose-cast both weights ----------------
// blocks [0,3072): cast tokens; [3072,4800): transpose wqkv; [4800,5376): transpose wproj
__global__ __launch_bounds__(256) void k_prep(
    const float* __restrict__ tokens, const float* __restrict__ wqkv,
    const float* __restrict__ wproj, unsigned short* __restrict__ tok,
    unsigned short* __restrict__ wqkvT, unsigned short* __restrict__ wprojT) {
  __shared__ float tile[32][33];
  const int b = blockIdx.x;
  const int tid = threadIdx.x;
  if (b < 3072) {
    int i = (b * 256 + tid) * 4;
    float4 v = *reinterpret_cast<const float4*>(tokens + i);
    u16x4 o;
    o.x = f2bf(v.x); o.y = f2bf(v.y); o.z = f2bf(v.z); o.w = f2bf(v.w);
    *reinterpret_cast<u16x4*>(tok + i) = o;
    return;
  }
  const float* in;
  unsigned short* out;
  int idx, N;
  if (b < 4800) { idx = b - 3072; in = wqkv;  out = wqkvT;  N = 2304; }
  else          { idx = b - 4800; in = wproj; out = wprojT; N = 768;  }
  const int k0 = (idx % 24) * 32, n0 = (idx / 24) * 32;
  const int tr = tid >> 5, tc = tid & 31;
#pragma unroll
  for (int i = 0; i < 4; i++)
    tile[i * 8 + tr][tc] = in[(k0 + i * 8 + tr) * N + n0 + tc];
  __syncthreads();
#pragma unroll
  for (int i = 0; i < 4; i++)
    out[(n0 + i * 8 + tr) * 768 + k0 + tc] = f2bf(tile[tc][i * 8 + tr]);
}

// ---------------- 128x128 bf16 MFMA GEMM (round-10 proven form) ----------------
// A[M][768] @ BT[N][768]^T, single-buffered (rounds 11/14: explicit dbuf,
// launch-bound caps, XCD swizzle, fused-merge A-path all regressed).
// MODE 0: QKV epilogue -> Q (pre-scaled by QSCL) / K row-major bf16, V transposed
// MODE 1: fp32 output + bias
template<int MODE>
__global__ __launch_bounds__(256) void k_gemm(
    const unsigned short* __restrict__ A, const unsigned short* __restrict__ BT,
    const float* __restrict__ bias,
    unsigned short* __restrict__ Oq, unsigned short* __restrict__ Ok,
    unsigned short* __restrict__ Ov, float* __restrict__ Of) {
  __shared__ unsigned short As[128 * 32];
  __shared__ unsigned short Bs[128 * 32];
  const int tid = threadIdx.x;
  const int lane = tid & 63;
  const int w = tid >> 6;
  const int wm = w >> 1, wn = w & 1;
  const int l15 = lane & 15, l4 = lane >> 4;
  const int m0 = blockIdx.x * 128, n0 = blockIdx.y * 128;

  f32x4 acc[4][4] = {};

  int srow[2], skc[2];
#pragma unroll
  for (int j = 0; j < 2; j++) {
    int slot = j * 256 + tid;
    srow[j] = slot >> 2;
    skc[j] = (slot & 3) ^ ((srow[j] >> 1) & 3);
  }
  const int ldsb0 = (tid & ~63) * 16;
  const int ldsb1 = (256 + (tid & ~63)) * 16;

  for (int k0 = 0; k0 < DM; k0 += 32) {
    gload16(A + (m0 + srow[0]) * DM + k0 + skc[0] * 8, (char*)As + ldsb0);
    gload16(A + (m0 + srow[1]) * DM + k0 + skc[1] * 8, (char*)As + ldsb1);
    gload16(BT + (n0 + srow[0]) * DM + k0 + skc[0] * 8, (char*)Bs + ldsb0);
    gload16(BT + (n0 + srow[1]) * DM + k0 + skc[1] * 8, (char*)Bs + ldsb1);
    __syncthreads();
    s8v af[4], bfr[4];
#pragma unroll
    for (int i = 0; i < 4; i++) {
      int ra = wm * 64 + i * 16 + l15;
      int ca = (l4 ^ ((ra >> 1) & 3)) * 8;
      af[i] = *reinterpret_cast<const s8v*>(&As[ra * 32 + ca]);
      int rb = wn * 64 + i * 16 + l15;
      int cb = (l4 ^ ((rb >> 1) & 3)) * 8;
      bfr[i] = *reinterpret_cast<const s8v*>(&Bs[rb * 32 + cb]);
    }
#pragma unroll
    for (int mi = 0; mi < 4; mi++)
#pragma unroll
      for (int nj = 0; nj < 4; nj++)
        acc[mi][nj] = __builtin_amdgcn_mfma_f32_16x16x32_bf16(af[mi], bfr[nj], acc[mi][nj], 0, 0, 0);
    __syncthreads();
  }

#pragma unroll
  for (int nj = 0; nj < 4; nj++) {
    const int col = n0 + wn * 64 + nj * 16 + l15;
    const float bv = bias[col];
#pragma unroll
    for (int mi = 0; mi < 4; mi++) {
      const int rowb = m0 + wm * 64 + mi * 16 + l4 * 4;
      if (MODE == 0) {
        if (col < 768) {
#pragma unroll
          for (int r = 0; r < 4; r++)
            Oq[(rowb + r) * DM + col] = f2bf((acc[mi][nj][r] + bv) * QSCL);
        } else if (col < 1536) {
#pragma unroll
          for (int r = 0; r < 4; r++)
            Ok[(rowb + r) * DM + (col - 768)] = f2bf(acc[mi][nj][r] + bv);
        } else {
          u16x4 pk;
#pragma unroll
          for (int r = 0; r < 4; r++)
            pk[r] = f2bf(acc[mi][nj][r] + bv);
          *reinterpret_cast<u16x4*>(&Ov[(col - 1536) * SEQ + rowb]) = pk;
        }
      } else {
#pragma unroll
        for (int r = 0; r < 4; r++)
          Of[(rowb + r) * DM + col] = acc[mi][nj][r] + bv;
      }
    }
  }
}

// ---------------- causal flash attention: 32x32 MFMA, fixed-m softmax, 4-way split ----
// Block (qt, head, s): 128 q-rows, key-tiles t ≡ s (mod 4). 4 waves x 32 q-rows.
// Swapped QK^T (mfma32(K,Q)): S^T[key][q], q = lane&31 lane-local. Fixed-offset
// softmax P = exp2(p - 8), with -8 FOLDED INTO THE MFMA C-INIT (saves 32 subs).
// Row-sums accumulate as f32x2 pairs (v_pk_add_f32). Staging addresses are
// uniform-base + 32-bit lane offset, incremented by constants (saddr form).
// s_setprio(1) wraps the MFMA clusters (T5; 4 independent blocks/CU).
// Partials (f16 O, f32 l) -> workspace; k_merge sums (no exp-weighting needed).
// Rounds 15/16 lessons: static heavy-first grid beats uniform-pairing (lower
// residency ceiling) and dynamic queues (L2/L3 thrash: FETCH 18.5->80MB).
__global__ __launch_bounds__(256, 4) void k_attn(
    const unsigned short* __restrict__ Qb, const unsigned short* __restrict__ Kb,
    const unsigned short* __restrict__ Vt, _Float16* __restrict__ Opart,
    float* __restrict__ lw) {
  __shared__ unsigned short Ks[2][64 * 64];   // [key][d], slot-swizzled, 8KB each
  __shared__ unsigned short Vs[2][64 * 64];   // [d][key], slot-swizzled, 8KB each
  const int tid = threadIdx.x;
  const int lane = tid & 63;
  const int w = tid >> 6;
  const int l31 = lane & 31, lh = lane >> 5;
  const int bid = blockIdx.x;
  const int s = bid & 3;                 // key-split index
  const int b2 = bid >> 2;
  const int head = b2 % NH;
  const int qt = 31 - (b2 / NH);         // heavy q-tiles dispatch first
  const int q0w = qt * 128 + w * 32;     // this wave's first q-row
  const int ntiles = 2 * qt + 2;

  const unsigned short* const Kh = Kb + head * HD;
  const unsigned short* const Vh = Vt + head * HD * SEQ;

  int srow[2], scol[2];
#pragma unroll
  for (int j = 0; j < 2; j++) {
    int c = j * 256 + tid;
    srow[j] = c >> 3;
    scol[j] = ((c & 7) ^ (srow[j] & 7)) * 8;
  }
  const int ldsoff0 = (tid & ~63) * 16;
  const int ldsoff1 = 4096 + (tid & ~63) * 16;
  int koff0 = (s * 64 + srow[0]) * DM + scol[0];
  int koff1 = (s * 64 + srow[1]) * DM + scol[1];
  int voff0 = srow[0] * SEQ + s * 64 + scol[0];
  int voff1 = srow[1] * SEQ + s * 64 + scol[1];

  s8v aq[4];
#pragma unroll
  for (int kc = 0; kc < 4; kc++)
    aq[kc] = *reinterpret_cast<const s8v*>(
        &Qb[(q0w + l31) * DM + head * HD + kc * 16 + lh * 8]);

  const int x7 = l31 & 7;
  const int rbase = l31 * 128;

  f32x16 O0 = {}, O1 = {};   // O^T[d][q]: d = db*32 + (r&3)+8*(r>>2)+4*lh, q = l31
  float lsum = 0.f;

  if (s < ntiles) {
    gload16(Kh + koff0, (char*)Ks[0] + ldsoff0);
    gload16(Kh + koff1, (char*)Ks[0] + ldsoff1);
    gload16(Vh + voff0, (char*)Vs[0] + ldsoff0);
    gload16(Vh + voff1, (char*)Vs[0] + ldsoff1);
    __asm__ volatile("s_waitcnt vmcnt(0)" ::: "memory");
  }
  __syncthreads();
  koff0 += 256 * DM; koff1 += 256 * DM;
  voff0 += 256;      voff1 += 256;

  for (int t = s; t < ntiles; t += 4) {
    const int cur = ((t - s) >> 2) & 1;
    if (t + 4 < ntiles) {
      const int nxt = cur ^ 1;
      gload16(Kh + koff0, (char*)Ks[nxt] + ldsoff0);
      gload16(Kh + koff1, (char*)Ks[nxt] + ldsoff1);
      gload16(Vh + voff0, (char*)Vs[nxt] + ldsoff0);
      gload16(Vh + voff1, (char*)Vs[nxt] + ldsoff1);
    }
    koff0 += 256 * DM; koff1 += 256 * DM;
    voff0 += 256;      voff1 += 256;
    const int kb = t * 64;
    if (kb <= q0w + 31) {
      const char* const kbuf = (const char*)Ks[cur];
      const char* const vbuf = (const char*)Vs[cur];
      f32x16 z0, z1;
#pragma unroll
      for (int r = 0; r < 16; r++) { z0[r] = -FOFF; z1[r] = -FOFF; }
      __builtin_amdgcn_s_setprio(1);
#pragma unroll
      for (int kc = 0; kc < 4; kc++) {
        const int so = ((kc * 2 + lh) ^ x7) << 4;
        const s8v k0 = *reinterpret_cast<const s8v*>(kbuf + rbase + so);
        const s8v k1 = *reinterpret_cast<const s8v*>(kbuf + 4096 + rbase + so);
        z0 = __builtin_amdgcn_mfma_f32_32x32x16_bf16(k0, aq[kc], z0, 0, 0, 0);
        z1 = __builtin_amdgcn_mfma_f32_32x32x16_bf16(k1, aq[kc], z1, 0, 0, 0);
      }
      __builtin_amdgcn_s_setprio(0);
      if (kb + 63 > q0w) {
        const int qm = q0w + l31 - kb - 4 * lh;   // mask if koff > qm
#pragma unroll
        for (int r = 0; r < 16; r++) {
          const int koff = (r & 3) + 8 * (r >> 2);
          z0[r] = (koff > qm) ? -1e30f : z0[r];
          z1[r] = (koff + 32 > qm) ? -1e30f : z1[r];
        }
      }
      f32x2 sa = {0.f, 0.f}, sb = {0.f, 0.f};
#pragma unroll
      for (int r = 0; r < 8; r++) {
        z0[2 * r] = exp2f(z0[2 * r]);
        z0[2 * r + 1] = exp2f(z0[2 * r + 1]);
        f32x2 e0; e0[0] = z0[2 * r]; e0[1] = z0[2 * r + 1];
        sa += e0;
        z1[2 * r] = exp2f(z1[2 * r]);
        z1[2 * r + 1] = exp2f(z1[2 * r + 1]);
        f32x2 e1; e1[0] = z1[2 * r]; e1[1] = z1[2 * r + 1];
        sb += e1;
      }
      sa += sb;
      lsum += sa[0] + sa[1];
      s8v pf[4];
#define PACKKC(V, base, dst)                                                 \
      {                                                                      \
        unsigned int A0 = cvtpk(V[base + 0], V[base + 1]);                   \
        unsigned int B0 = cvtpk(V[base + 2], V[base + 3]);                   \
        unsigned int A1 = cvtpk(V[base + 4], V[base + 5]);                   \
        unsigned int B1 = cvtpk(V[base + 6], V[base + 7]);                   \
        asm("v_permlane32_swap_b32 %0, %1" : "+v"(A0), "+v"(A1));            \
        asm("v_permlane32_swap_b32 %0, %1" : "+v"(B0), "+v"(B1));            \
        u32x4 q_ = {A0, B0, A1, B1};                                         \
        dst = __builtin_bit_cast(s8v, q_);                                   \
      }
      PACKKC(z0, 0, pf[0]);
      PACKKC(z0, 8, pf[1]);
      PACKKC(z1, 0, pf[2]);
      PACKKC(z1, 8, pf[3]);
#undef PACKKC
      __builtin_amdgcn_s_setprio(1);
#pragma unroll
      for (int kc = 0; kc < 4; kc++) {
        const int so = ((kc * 2 + lh) ^ x7) << 4;
        const s8v v0 = *reinterpret_cast<const s8v*>(vbuf + rbase + so);
        const s8v v1 = *reinterpret_cast<const s8v*>(vbuf + 4096 + rbase + so);
        O0 = __builtin_amdgcn_mfma_f32_32x32x16_bf16(v0, pf[kc], O0, 0, 0, 0);
        O1 = __builtin_amdgcn_mfma_f32_32x32x16_bf16(v1, pf[kc], O1, 0, 0, 0);
      }
      __builtin_amdgcn_s_setprio(0);
    }
    __asm__ volatile("s_waitcnt vmcnt(0)" ::: "memory");
    __syncthreads();
  }

  lsum += __shfl_xor(lsum, 32);
  _Float16* const op = Opart + (size_t)s * SEQ * DM + (size_t)(q0w + l31) * DM +
                       head * HD + 4 * lh;
#pragma unroll
  for (int k = 0; k < 4; k++) {
    h16x4 o0h, o1h;
#pragma unroll
    for (int r = 0; r < 4; r++) {
      o0h[r] = (_Float16)O0[k * 4 + r];
      o1h[r] = (_Float16)O1[k * 4 + r];
    }
    *reinterpret_cast<h16x4*>(op + 8 * k) = o0h;        // d = 8k + 4lh + r
    *reinterpret_cast<h16x4*>(op + 32 + 8 * k) = o1h;   // d = 32 + 8k + 4lh + r
  }
  if (lh == 0)
    lw[(s * NH + head) * SEQ + q0w + l31] = lsum;
}

// ---------------- merge the 4 key-split partials (plain sums) -> bf16 attn ----------------
__global__ __launch_bounds__(256) void k_merge(const _Float16* __restrict__ Opart,
                                               const float* __restrict__ lw,
                                               unsigned short* __restrict__ attn) {
  const int idx = blockIdx.x * 256 + threadIdx.x;
  const int e4 = idx * 4;                   // 4 consecutive d-elements
  const int row = e4 / DM;
  const int col = e4 - row * DM;
  const int head = col >> 6;
  const float l0 = lw[(0 * NH + head) * SEQ + row];
  const float l1 = lw[(1 * NH + head) * SEQ + row];
  const float l2 = lw[(2 * NH + head) * SEQ + row];
  const float l3 = lw[(3 * NH + head) * SEQ + row];
  const float rl = 1.f / (l0 + l1 + l2 + l3);
  const size_t SD = (size_t)SEQ * DM;
  const h16x4 o0 = *reinterpret_cast<const h16x4*>(Opart + e4);
  const h16x4 o1 = *reinterpret_cast<const h16x4*>(Opart + SD + e4);
  const h16x4 o2 = *reinterpret_cast<const h16x4*>(Opart + 2 * SD + e4);
  const h16x4 o3 = *reinterpret_cast<const h16x4*>(Opart + 3 * SD + e4);
  u16x4 pk;
#pragma unroll
  for (int j = 0; j < 4; j++)
    pk[j] = f2bf(((float)o0[j] + (float)o1[j] + (float)o2[j] + (float)o3[j]) * rl);
  *reinterpret_cast<u16x4*>(attn + e4) = pk;
}

extern "C" void kernel_launch(void* const* d_in, const int* in_sizes, int n_in,
                              void* d_out, int out_size, void* d_ws, size_t ws_size,
                              hipStream_t stream) {
  (void)in_sizes; (void)n_in; (void)out_size; (void)ws_size;
  const float* tokens = (const float*)d_in[0];
  const float* wqkv  = (const float*)d_in[2];
  const float* bqkv  = (const float*)d_in[3];
  const float* wproj = (const float*)d_in[4];
  const float* bproj = (const float*)d_in[5];
  float* out = (float*)d_out;

  unsigned short* tok    = (unsigned short*)d_ws;       // [4096][768]
  unsigned short* wqkvT  = tok + 4096 * 768;            // [2304][768]
  unsigned short* wprojT = wqkvT + 2304 * 768;          // [768][768]
  unsigned short* Qb     = wprojT + 768 * 768;          // [4096][768] (pre-scaled)
  unsigned short* Kb     = Qb + 4096 * 768;             // [4096][768]
  unsigned short* Vt     = Kb + 4096 * 768;             // [768][4096]
  unsigned short* attn   = Vt + 768 * 4096;             // [4096][768]
  _Float16* Opart = (_Float16*)(attn + 4096 * 768);     // 4 x [4096][768] f16
  float* lw = (float*)(Opart + 4 * (size_t)4096 * 768); // 4 x 12 x 4096 f32

  k_prep<<<5376, 256, 0, stream>>>(tokens, wqkv, wproj, tok, wqkvT, wprojT);
  k_gemm<0><<<dim3(32, 18), 256, 0, stream>>>(tok, wqkvT, bqkv, Qb, Kb, Vt, nullptr);
  k_attn<<<1536, 256, 0, stream>>>(Qb, Kb, Vt, Opart, lw);
  k_merge<<<3072, 256, 0, stream>>>(Opart, lw, attn);
  k_gemm<1><<<dim3(32, 6), 256, 0, stream>>>(attn, wprojT, bproj, nullptr, nullptr, nullptr, out);
}

// Round 18
// 101.816 us; speedup vs baseline: 1.3031x; 1.0205x over previous
//
#include <hip/hip_runtime.h>

typedef __attribute__((ext_vector_type(8))) short s8v;        // 8 x bf16 bits
typedef __attribute__((ext_vector_type(2))) float f32x2;
typedef __attribute__((ext_vector_type(4))) float f32x4;
typedef __attribute__((ext_vector_type(16))) float f32x16;
typedef __attribute__((ext_vector_type(4))) unsigned short u16x4;
typedef __attribute__((ext_vector_type(4))) unsigned int u32x4;
typedef __attribute__((ext_vector_type(4))) _Float16 h16x4;

#define SEQ 4096
#define DM  768
#define NH  12
#define HD  64
#define QSCL 0.18033688f   // (1/sqrt(64)) * log2(e), folded into Q at QKV epilogue
#define FOFF 8.0f          // fixed softmax offset (log2 domain): P = exp2(p - 8)

__device__ __forceinline__ unsigned short f2bf(float f) {
  union { float f; unsigned int u; } v; v.f = f;
  unsigned int r = v.u + 0x7fffu + ((v.u >> 16) & 1u);
  return (unsigned short)(r >> 16);
}

__device__ __forceinline__ unsigned int cvtpk(float lo, float hi) {
  unsigned int r;
  asm("v_cvt_pk_bf16_f32 %0, %1, %2" : "=v"(r) : "v"(lo), "v"(hi));
  return r;
}

__device__ __forceinline__ void gload16(const void* g, void* l) {
  __builtin_amdgcn_global_load_lds((const __attribute__((address_space(1))) void*)g,
                                   (__attribute__((address_space(3))) void*)l, 16, 0, 0);
}

// ---------------- fused prep: cast tokens + transpose-cast both weights ----------------
// blocks [0,3072): cast tokens; [3072,4800): transpose wqkv; [4800,5376): transpose wproj
__global__ __launch_bounds__(256) void k_prep(
    const float* __restrict__ tokens, const float* __restrict__ wqkv,
    const float* __restrict__ wproj, unsigned short* __restrict__ tok,
    unsigned short* __restrict__ wqkvT, unsigned short* __restrict__ wprojT) {
  __shared__ float tile[32][33];
  const int b = blockIdx.x;
  const int tid = threadIdx.x;
  if (b < 3072) {
    int i = (b * 256 + tid) * 4;
    float4 v = *reinterpret_cast<const float4*>(tokens + i);
    u16x4 o;
    o.x = f2bf(v.x); o.y = f2bf(v.y); o.z = f2bf(v.z); o.w = f2bf(v.w);
    *reinterpret_cast<u16x4*>(tok + i) = o;
    return;
  }
  const float* in;
  unsigned short* out;
  int idx, N;
  if (b < 4800) { idx = b - 3072; in = wqkv;  out = wqkvT;  N = 2304; }
  else          { idx = b - 4800; in = wproj; out = wprojT; N = 768;  }
  const int k0 = (idx % 24) * 32, n0 = (idx / 24) * 32;
  const int tr = tid >> 5, tc = tid & 31;
#pragma unroll
  for (int i = 0; i < 4; i++)
    tile[i * 8 + tr][tc] = in[(k0 + i * 8 + tr) * N + n0 + tc];
  __syncthreads();
#pragma unroll
  for (int i = 0; i < 4; i++)
    out[(n0 + i * 8 + tr) * 768 + k0 + tc] = f2bf(tile[tc][i * 8 + tr]);
}

// ---------------- BM x BN bf16 MFMA GEMM (round-10 inner structure) ----------------
// A[M][768] @ BT[N][768]^T, single-buffered. Round-18: tile sizes re-parameterized
// so both GEMMs get enough RESIDENT blocks to hide staging latency (round-10 ran
// gemm0 at 2.25 blocks/CU, gemm1 at 0.75 -- latency-bound). Inner structure is
// byte-identical (same slot swizzle, same frag reads, same barrier pattern).
// MODE 0: QKV epilogue -> Q (pre-scaled by QSCL) / K row-major bf16, V transposed
// MODE 1: fp32 output + bias
template<int BM, int BN, int MODE>
__global__ __launch_bounds__(256) void k_gemm(
    const unsigned short* __restrict__ A, const unsigned short* __restrict__ BT,
    const float* __restrict__ bias,
    unsigned short* __restrict__ Oq, unsigned short* __restrict__ Ok,
    unsigned short* __restrict__ Ov, float* __restrict__ Of) {
  __shared__ unsigned short As[BM * 32];
  __shared__ unsigned short Bs[BN * 32];
  const int tid = threadIdx.x;
  const int lane = tid & 63;
  const int w = tid >> 6;
  const int wm = w >> 1, wn = w & 1;
  const int l15 = lane & 15, l4 = lane >> 4;
  const int m0 = blockIdx.x * BM, n0 = blockIdx.y * BN;
  constexpr int MF = BM / 32, NF = BN / 32;    // frags per wave per dim

  f32x4 acc[MF][NF] = {};

  for (int k0 = 0; k0 < DM; k0 += 32) {
    // stage A chunks (BM*4 x 16B), slot-swizzled: lds slot c holds k-chunk (c&3)^((row>>1)&3)
#pragma unroll
    for (int c0 = 0; c0 < BM * 4; c0 += 256) {
      const int c = c0 + tid;
      const int row = c >> 2;
      const int col8 = ((c & 3) ^ ((row >> 1) & 3)) * 8;
      gload16(A + (m0 + row) * DM + k0 + col8, (char*)As + (c0 + (tid & ~63)) * 16);
    }
    // stage B chunks (BN*4 x 16B)
#pragma unroll
    for (int c0 = 0; c0 < BN * 4; c0 += 256) {
      const int c = c0 + tid;
      const int row = c >> 2;
      const int col8 = ((c & 3) ^ ((row >> 1) & 3)) * 8;
      gload16(BT + (n0 + row) * DM + k0 + col8, (char*)Bs + (c0 + (tid & ~63)) * 16);
    }
    __syncthreads();   // compiler emits vmcnt(0) drain before s_barrier
    s8v af[MF], bfr[NF];
#pragma unroll
    for (int i = 0; i < MF; i++) {
      const int ra = wm * (BM / 2) + i * 16 + l15;
      const int ca = (l4 ^ ((ra >> 1) & 3)) * 8;
      af[i] = *reinterpret_cast<const s8v*>(&As[ra * 32 + ca]);
    }
#pragma unroll
    for (int j = 0; j < NF; j++) {
      const int rb = wn * (BN / 2) + j * 16 + l15;
      const int cb = (l4 ^ ((rb >> 1) & 3)) * 8;
      bfr[j] = *reinterpret_cast<const s8v*>(&Bs[rb * 32 + cb]);
    }
#pragma unroll
    for (int mi = 0; mi < MF; mi++)
#pragma unroll
      for (int nj = 0; nj < NF; nj++)
        acc[mi][nj] = __builtin_amdgcn_mfma_f32_16x16x32_bf16(af[mi], bfr[nj], acc[mi][nj], 0, 0, 0);
    __syncthreads();
  }

#pragma unroll
  for (int nj = 0; nj < NF; nj++) {
    const int col = n0 + wn * (BN / 2) + nj * 16 + l15;
    const float bv = bias[col];
#pragma unroll
    for (int mi = 0; mi < MF; mi++) {
      const int rowb = m0 + wm * (BM / 2) + mi * 16 + l4 * 4;
      if (MODE == 0) {
        if (col < 768) {
#pragma unroll
          for (int r = 0; r < 4; r++)
            Oq[(rowb + r) * DM + col] = f2bf((acc[mi][nj][r] + bv) * QSCL);
        } else if (col < 1536) {
#pragma unroll
          for (int r = 0; r < 4; r++)
            Ok[(rowb + r) * DM + (col - 768)] = f2bf(acc[mi][nj][r] + bv);
        } else {
          u16x4 pk;
#pragma unroll
          for (int r = 0; r < 4; r++)
            pk[r] = f2bf(acc[mi][nj][r] + bv);
          *reinterpret_cast<u16x4*>(&Ov[(col - 1536) * SEQ + rowb]) = pk;
        }
      } else {
#pragma unroll
        for (int r = 0; r < 4; r++)
          Of[(rowb + r) * DM + col] = acc[mi][nj][r] + bv;
      }
    }
  }
}

// ---------------- causal flash attention: 32x32 MFMA, fixed-m softmax, 4-way split ----
// (byte-identical to rounds 10/17 -- proven best; k_attn is register-bound at
// 4 waves/SIMD and closed for this session)
__global__ __launch_bounds__(256, 4) void k_attn(
    const unsigned short* __restrict__ Qb, const unsigned short* __restrict__ Kb,
    const unsigned short* __restrict__ Vt, _Float16* __restrict__ Opart,
    float* __restrict__ lw) {
  __shared__ unsigned short Ks[2][64 * 64];   // [key][d], slot-swizzled, 8KB each
  __shared__ unsigned short Vs[2][64 * 64];   // [d][key], slot-swizzled, 8KB each
  const int tid = threadIdx.x;
  const int lane = tid & 63;
  const int w = tid >> 6;
  const int l31 = lane & 31, lh = lane >> 5;
  const int bid = blockIdx.x;
  const int s = bid & 3;                 // key-split index
  const int b2 = bid >> 2;
  const int head = b2 % NH;
  const int qt = 31 - (b2 / NH);         // heavy q-tiles dispatch first
  const int q0w = qt * 128 + w * 32;     // this wave's first q-row
  const int ntiles = 2 * qt + 2;

  const unsigned short* const Kh = Kb + head * HD;
  const unsigned short* const Vh = Vt + head * HD * SEQ;

  int srow[2], scol[2];
#pragma unroll
  for (int j = 0; j < 2; j++) {
    int c = j * 256 + tid;
    srow[j] = c >> 3;
    scol[j] = ((c & 7) ^ (srow[j] & 7)) * 8;
  }
  const int ldsoff0 = (tid & ~63) * 16;
  const int ldsoff1 = 4096 + (tid & ~63) * 16;
  int koff0 = (s * 64 + srow[0]) * DM + scol[0];
  int koff1 = (s * 64 + srow[1]) * DM + scol[1];
  int voff0 = srow[0] * SEQ + s * 64 + scol[0];
  int voff1 = srow[1] * SEQ + s * 64 + scol[1];

  s8v aq[4];
#pragma unroll
  for (int kc = 0; kc < 4; kc++)
    aq[kc] = *reinterpret_cast<const s8v*>(
        &Qb[(q0w + l31) * DM + head * HD + kc * 16 + lh * 8]);

  const int x7 = l31 & 7;
  const int rbase = l31 * 128;

  f32x16 O0 = {}, O1 = {};   // O^T[d][q]: d = db*32 + (r&3)+8*(r>>2)+4*lh, q = l31
  float lsum = 0.f;

  if (s < ntiles) {
    gload16(Kh + koff0, (char*)Ks[0] + ldsoff0);
    gload16(Kh + koff1, (char*)Ks[0] + ldsoff1);
    gload16(Vh + voff0, (char*)Vs[0] + ldsoff0);
    gload16(Vh + voff1, (char*)Vs[0] + ldsoff1);
    __asm__ volatile("s_waitcnt vmcnt(0)" ::: "memory");
  }
  __syncthreads();
  koff0 += 256 * DM; koff1 += 256 * DM;
  voff0 += 256;      voff1 += 256;

  for (int t = s; t < ntiles; t += 4) {
    const int cur = ((t - s) >> 2) & 1;
    if (t + 4 < ntiles) {
      const int nxt = cur ^ 1;
      gload16(Kh + koff0, (char*)Ks[nxt] + ldsoff0);
      gload16(Kh + koff1, (char*)Ks[nxt] + ldsoff1);
      gload16(Vh + voff0, (char*)Vs[nxt] + ldsoff0);
      gload16(Vh + voff1, (char*)Vs[nxt] + ldsoff1);
    }
    koff0 += 256 * DM; koff1 += 256 * DM;
    voff0 += 256;      voff1 += 256;
    const int kb = t * 64;
    if (kb <= q0w + 31) {
      const char* const kbuf = (const char*)Ks[cur];
      const char* const vbuf = (const char*)Vs[cur];
      f32x16 z0, z1;
#pragma unroll
      for (int r = 0; r < 16; r++) { z0[r] = -FOFF; z1[r] = -FOFF; }
      __builtin_amdgcn_s_setprio(1);
#pragma unroll
      for (int kc = 0; kc < 4; kc++) {
        const int so = ((kc * 2 + lh) ^ x7) << 4;
        const s8v k0 = *reinterpret_cast<const s8v*>(kbuf + rbase + so);
        const s8v k1 = *reinterpret_cast<const s8v*>(kbuf + 4096 + rbase + so);
        z0 = __builtin_amdgcn_mfma_f32_32x32x16_bf16(k0, aq[kc], z0, 0, 0, 0);
        z1 = __builtin_amdgcn_mfma_f32_32x32x16_bf16(k1, aq[kc], z1, 0, 0, 0);
      }
      __builtin_amdgcn_s_setprio(0);
      if (kb + 63 > q0w) {
        const int qm = q0w + l31 - kb - 4 * lh;   // mask if koff > qm
#pragma unroll
        for (int r = 0; r < 16; r++) {
          const int koff = (r & 3) + 8 * (r >> 2);
          z0[r] = (koff > qm) ? -1e30f : z0[r];
          z1[r] = (koff + 32 > qm) ? -1e30f : z1[r];
        }
      }
      f32x2 sa = {0.f, 0.f}, sb = {0.f, 0.f};
#pragma unroll
      for (int r = 0; r < 8; r++) {
        z0[2 * r] = exp2f(z0[2 * r]);
        z0[2 * r + 1] = exp2f(z0[2 * r + 1]);
        f32x2 e0; e0[0] = z0[2 * r]; e0[1] = z0[2 * r + 1];
        sa += e0;
        z1[2 * r] = exp2f(z1[2 * r]);
        z1[2 * r + 1] = exp2f(z1[2 * r + 1]);
        f32x2 e1; e1[0] = z1[2 * r]; e1[1] = z1[2 * r + 1];
        sb += e1;
      }
      sa += sb;
      lsum += sa[0] + sa[1];
      s8v pf[4];
#define PACKKC(V, base, dst)                                                 \
      {                                                                      \
        unsigned int A0 = cvtpk(V[base + 0], V[base + 1]);                   \
        unsigned int B0 = cvtpk(V[base + 2], V[base + 3]);                   \
        unsigned int A1 = cvtpk(V[base + 4], V[base + 5]);                   \
        unsigned int B1 = cvtpk(V[base + 6], V[base + 7]);                   \
        asm("v_permlane32_swap_b32 %0, %1" : "+v"(A0), "+v"(A1));            \
        asm("v_permlane32_swap_b32 %0, %1" : "+v"(B0), "+v"(B1));            \
        u32x4 q_ = {A0, B0, A1, B1};                                         \
        dst = __builtin_bit_cast(s8v, q_);                                   \
      }
      PACKKC(z0, 0, pf[0]);
      PACKKC(z0, 8, pf[1]);
      PACKKC(z1, 0, pf[2]);
      PACKKC(z1, 8, pf[3]);
#undef PACKKC
      __builtin_amdgcn_s_setprio(1);
#pragma unroll
      for (int kc = 0; kc < 4; kc++) {
        const int so = ((kc * 2 + lh) ^ x7) << 4;
        const s8v v0 = *reinterpret_cast<const s8v*>(vbuf + rbase + so);
        const s8v v1 = *reinterpret_cast<const s8v*>(vbuf + 4096 + rbase + so);
        O0 = __builtin_amdgcn_mfma_f32_32x32x16_bf16(v0, pf[kc], O0, 0, 0, 0);
        O1 = __builtin_amdgcn_mfma_f32_32x32x16_bf16(v1, pf[kc], O1, 0, 0, 0);
      }
      __builtin_amdgcn_s_setprio(0);
    }
    __asm__ volatile("s_waitcnt vmcnt(0)" ::: "memory");
    __syncthreads();
  }

  lsum += __shfl_xor(lsum, 32);
  _Float16* const op = Opart + (size_t)s * SEQ * DM + (size_t)(q0w + l31) * DM +
                       head * HD + 4 * lh;
#pragma unroll
  for (int k = 0; k < 4; k++) {
    h16x4 o0h, o1h;
#pragma unroll
    for (int r = 0; r < 4; r++) {
      o0h[r] = (_Float16)O0[k * 4 + r];
      o1h[r] = (_Float16)O1[k * 4 + r];
    }
    *reinterpret_cast<h16x4*>(op + 8 * k) = o0h;        // d = 8k + 4lh + r
    *reinterpret_cast<h16x4*>(op + 32 + 8 * k) = o1h;   // d = 32 + 8k + 4lh + r
  }
  if (lh == 0)
    lw[(s * NH + head) * SEQ + q0w + l31] = lsum;
}

// ---------------- merge the 4 key-split partials (plain sums) -> bf16 attn ----------------
__global__ __launch_bounds__(256) void k_merge(const _Float16* __restrict__ Opart,
                                               const float* __restrict__ lw,
                                               unsigned short* __restrict__ attn) {
  const int idx = blockIdx.x * 256 + threadIdx.x;
  const int e4 = idx * 4;                   // 4 consecutive d-elements
  const int row = e4 / DM;
  const int col = e4 - row * DM;
  const int head = col >> 6;
  const float l0 = lw[(0 * NH + head) * SEQ + row];
  const float l1 = lw[(1 * NH + head) * SEQ + row];
  const float l2 = lw[(2 * NH + head) * SEQ + row];
  const float l3 = lw[(3 * NH + head) * SEQ + row];
  const float rl = 1.f / (l0 + l1 + l2 + l3);
  const size_t SD = (size_t)SEQ * DM;
  const h16x4 o0 = *reinterpret_cast<const h16x4*>(Opart + e4);
  const h16x4 o1 = *reinterpret_cast<const h16x4*>(Opart + SD + e4);
  const h16x4 o2 = *reinterpret_cast<const h16x4*>(Opart + 2 * SD + e4);
  const h16x4 o3 = *reinterpret_cast<const h16x4*>(Opart + 3 * SD + e4);
  u16x4 pk;
#pragma unroll
  for (int j = 0; j < 4; j++)
    pk[j] = f2bf(((float)o0[j] + (float)o1[j] + (float)o2[j] + (float)o3[j]) * rl);
  *reinterpret_cast<u16x4*>(attn + e4) = pk;
}

extern "C" void kernel_launch(void* const* d_in, const int* in_sizes, int n_in,
                              void* d_out, int out_size, void* d_ws, size_t ws_size,
                              hipStream_t stream) {
  (void)in_sizes; (void)n_in; (void)out_size; (void)ws_size;
  const float* tokens = (const float*)d_in[0];
  const float* wqkv  = (const float*)d_in[2];
  const float* bqkv  = (const float*)d_in[3];
  const float* wproj = (const float*)d_in[4];
  const float* bproj = (const float*)d_in[5];
  float* out = (float*)d_out;

  unsigned short* tok    = (unsigned short*)d_ws;       // [4096][768]
  unsigned short* wqkvT  = tok + 4096 * 768;            // [2304][768]
  unsigned short* wprojT = wqkvT + 2304 * 768;          // [768][768]
  unsigned short* Qb     = wprojT + 768 * 768;          // [4096][768] (pre-scaled)
  unsigned short* Kb     = Qb + 4096 * 768;             // [4096][768]
  unsigned short* Vt     = Kb + 4096 * 768;             // [768][4096]
  unsigned short* attn   = Vt + 768 * 4096;             // [4096][768]
  _Float16* Opart = (_Float16*)(attn + 4096 * 768);     // 4 x [4096][768] f16
  float* lw = (float*)(Opart + 4 * (size_t)4096 * 768); // 4 x 12 x 4096 f32

  k_prep<<<5376, 256, 0, stream>>>(tokens, wqkv, wproj, tok, wqkvT, wprojT);
  k_gemm<128, 64, 0><<<dim3(32, 36), 256, 0, stream>>>(tok, wqkvT, bqkv, Qb, Kb, Vt, nullptr);
  k_attn<<<1536, 256, 0, stream>>>(Qb, Kb, Vt, Opart, lw);
  k_merge<<<3072, 256, 0, stream>>>(Opart, lw, attn);
  k_gemm<64, 64, 1><<<dim3(64, 12), 256, 0, stream>>>(attn, wprojT, bproj, nullptr, nullptr, nullptr, out);
}

// Round 19
// 101.713 us; speedup vs baseline: 1.3044x; 1.0010x over previous
//
#include <hip/hip_runtime.h>

typedef __attribute__((ext_vector_type(8))) short s8v;        // 8 x bf16 bits
typedef __attribute__((ext_vector_type(2))) float f32x2;
typedef __attribute__((ext_vector_type(4))) float f32x4;
typedef __attribute__((ext_vector_type(16))) float f32x16;
typedef __attribute__((ext_vector_type(4))) unsigned short u16x4;
typedef __attribute__((ext_vector_type(4))) unsigned int u32x4;
typedef __attribute__((ext_vector_type(4))) _Float16 h16x4;

#define SEQ 4096
#define DM  768
#define NH  12
#define HD  64
#define QSCL 0.18033688f   // (1/sqrt(64)) * log2(e), folded into Q at QKV epilogue
#define FOFF 8.0f          // fixed softmax offset (log2 domain): P = exp2(p - 8)

__device__ __forceinline__ unsigned short f2bf(float f) {
  union { float f; unsigned int u; } v; v.f = f;
  unsigned int r = v.u + 0x7fffu + ((v.u >> 16) & 1u);
  return (unsigned short)(r >> 16);
}

__device__ __forceinline__ unsigned int cvtpk(float lo, float hi) {
  unsigned int r;
  asm("v_cvt_pk_bf16_f32 %0, %1, %2" : "=v"(r) : "v"(lo), "v"(hi));
  return r;
}

__device__ __forceinline__ void gload16(const void* g, void* l) {
  __builtin_amdgcn_global_load_lds((const __attribute__((address_space(1))) void*)g,
                                   (__attribute__((address_space(3))) void*)l, 16, 0, 0);
}

// ---------------- fused prep: cast tokens + transpose-cast both weights ----------------
// blocks [0,3072): cast tokens; [3072,4800): transpose wqkv; [4800,5376): transpose wproj
__global__ __launch_bounds__(256) void k_prep(
    const float* __restrict__ tokens, const float* __restrict__ wqkv,
    const float* __restrict__ wproj, unsigned short* __restrict__ tok,
    unsigned short* __restrict__ wqkvT, unsigned short* __restrict__ wprojT) {
  __shared__ float tile[32][33];
  const int b = blockIdx.x;
  const int tid = threadIdx.x;
  if (b < 3072) {
    int i = (b * 256 + tid) * 4;
    float4 v = *reinterpret_cast<const float4*>(tokens + i);
    u16x4 o;
    o.x = f2bf(v.x); o.y = f2bf(v.y); o.z = f2bf(v.z); o.w = f2bf(v.w);
    *reinterpret_cast<u16x4*>(tok + i) = o;
    return;
  }
  const float* in;
  unsigned short* out;
  int idx, N;
  if (b < 4800) { idx = b - 3072; in = wqkv;  out = wqkvT;  N = 2304; }
  else          { idx = b - 4800; in = wproj; out = wprojT; N = 768;  }
  const int k0 = (idx % 24) * 32, n0 = (idx / 24) * 32;
  const int tr = tid >> 5, tc = tid & 31;
#pragma unroll
  for (int i = 0; i < 4; i++)
    tile[i * 8 + tr][tc] = in[(k0 + i * 8 + tr) * N + n0 + tc];
  __syncthreads();
#pragma unroll
  for (int i = 0; i < 4; i++)
    out[(n0 + i * 8 + tr) * 768 + k0 + tc] = f2bf(tile[tc][i * 8 + tr]);
}

// ---------------- BM x BN bf16 MFMA GEMM (round-18 proven tiles) ----------------
// A[M][768] @ BT[N][768]^T, single-buffered. gemm0 = 128x64 (4.5 blocks/CU),
// gemm1 = 64x64 (3 blocks/CU). Inner structure is the round-10 proven form.
// MODE 0: QKV epilogue -> Q (pre-scaled by QSCL) / K row-major bf16, V transposed
// MODE 1: fp32 output + bias
template<int BM, int BN, int MODE>
__global__ __launch_bounds__(256) void k_gemm(
    const unsigned short* __restrict__ A, const unsigned short* __restrict__ BT,
    const float* __restrict__ bias,
    unsigned short* __restrict__ Oq, unsigned short* __restrict__ Ok,
    unsigned short* __restrict__ Ov, float* __restrict__ Of) {
  __shared__ unsigned short As[BM * 32];
  __shared__ unsigned short Bs[BN * 32];
  const int tid = threadIdx.x;
  const int lane = tid & 63;
  const int w = tid >> 6;
  const int wm = w >> 1, wn = w & 1;
  const int l15 = lane & 15, l4 = lane >> 4;
  const int m0 = blockIdx.x * BM, n0 = blockIdx.y * BN;
  constexpr int MF = BM / 32, NF = BN / 32;    // frags per wave per dim

  f32x4 acc[MF][NF] = {};

  for (int k0 = 0; k0 < DM; k0 += 32) {
    // stage A chunks (BM*4 x 16B), slot-swizzled: lds slot c holds k-chunk (c&3)^((row>>1)&3)
#pragma unroll
    for (int c0 = 0; c0 < BM * 4; c0 += 256) {
      const int c = c0 + tid;
      const int row = c >> 2;
      const int col8 = ((c & 3) ^ ((row >> 1) & 3)) * 8;
      gload16(A + (m0 + row) * DM + k0 + col8, (char*)As + (c0 + (tid & ~63)) * 16);
    }
    // stage B chunks (BN*4 x 16B)
#pragma unroll
    for (int c0 = 0; c0 < BN * 4; c0 += 256) {
      const int c = c0 + tid;
      const int row = c >> 2;
      const int col8 = ((c & 3) ^ ((row >> 1) & 3)) * 8;
      gload16(BT + (n0 + row) * DM + k0 + col8, (char*)Bs + (c0 + (tid & ~63)) * 16);
    }
    __syncthreads();   // compiler emits vmcnt(0) drain before s_barrier
    s8v af[MF], bfr[NF];
#pragma unroll
    for (int i = 0; i < MF; i++) {
      const int ra = wm * (BM / 2) + i * 16 + l15;
      const int ca = (l4 ^ ((ra >> 1) & 3)) * 8;
      af[i] = *reinterpret_cast<const s8v*>(&As[ra * 32 + ca]);
    }
#pragma unroll
    for (int j = 0; j < NF; j++) {
      const int rb = wn * (BN / 2) + j * 16 + l15;
      const int cb = (l4 ^ ((rb >> 1) & 3)) * 8;
      bfr[j] = *reinterpret_cast<const s8v*>(&Bs[rb * 32 + cb]);
    }
#pragma unroll
    for (int mi = 0; mi < MF; mi++)
#pragma unroll
      for (int nj = 0; nj < NF; nj++)
        acc[mi][nj] = __builtin_amdgcn_mfma_f32_16x16x32_bf16(af[mi], bfr[nj], acc[mi][nj], 0, 0, 0);
    __syncthreads();
  }

#pragma unroll
  for (int nj = 0; nj < NF; nj++) {
    const int col = n0 + wn * (BN / 2) + nj * 16 + l15;
    const float bv = bias[col];
#pragma unroll
    for (int mi = 0; mi < MF; mi++) {
      const int rowb = m0 + wm * (BM / 2) + mi * 16 + l4 * 4;
      if (MODE == 0) {
        if (col < 768) {
#pragma unroll
          for (int r = 0; r < 4; r++)
            Oq[(rowb + r) * DM + col] = f2bf((acc[mi][nj][r] + bv) * QSCL);
        } else if (col < 1536) {
#pragma unroll
          for (int r = 0; r < 4; r++)
            Ok[(rowb + r) * DM + (col - 768)] = f2bf(acc[mi][nj][r] + bv);
        } else {
          u16x4 pk;
#pragma unroll
          for (int r = 0; r < 4; r++)
            pk[r] = f2bf(acc[mi][nj][r] + bv);
          *reinterpret_cast<u16x4*>(&Ov[(col - 1536) * SEQ + rowb]) = pk;
        }
      } else {
#pragma unroll
        for (int r = 0; r < 4; r++)
          Of[(rowb + r) * DM + col] = acc[mi][nj][r] + bv;
      }
    }
  }
}

// ---------------- causal flash attention: 32x32 MFMA, fixed-m softmax, 4-way split ----
// Round-19 micro: (a) accumulator init -FOFF hoisted to a loop-invariant minit
// vector consumed as the FIRST QK MFMA's C operand (kills 32 v_mov/tile);
// (b) s_setprio removed (lockstep 4-wave blocks = GEMM-like regime where m190
// measured setprio negative; it was never isolated here).
__global__ __launch_bounds__(256, 4) void k_attn(
    const unsigned short* __restrict__ Qb, const unsigned short* __restrict__ Kb,
    const unsigned short* __restrict__ Vt, _Float16* __restrict__ Opart,
    float* __restrict__ lw) {
  __shared__ unsigned short Ks[2][64 * 64];   // [key][d], slot-swizzled, 8KB each
  __shared__ unsigned short Vs[2][64 * 64];   // [d][key], slot-swizzled, 8KB each
  const int tid = threadIdx.x;
  const int lane = tid & 63;
  const int w = tid >> 6;
  const int l31 = lane & 31, lh = lane >> 5;
  const int bid = blockIdx.x;
  const int s = bid & 3;                 // key-split index
  const int b2 = bid >> 2;
  const int head = b2 % NH;
  const int qt = 31 - (b2 / NH);         // heavy q-tiles dispatch first
  const int q0w = qt * 128 + w * 32;     // this wave's first q-row
  const int ntiles = 2 * qt + 2;

  const unsigned short* const Kh = Kb + head * HD;
  const unsigned short* const Vh = Vt + head * HD * SEQ;

  int srow[2], scol[2];
#pragma unroll
  for (int j = 0; j < 2; j++) {
    int c = j * 256 + tid;
    srow[j] = c >> 3;
    scol[j] = ((c & 7) ^ (srow[j] & 7)) * 8;
  }
  const int ldsoff0 = (tid & ~63) * 16;
  const int ldsoff1 = 4096 + (tid & ~63) * 16;
  int koff0 = (s * 64 + srow[0]) * DM + scol[0];
  int koff1 = (s * 64 + srow[1]) * DM + scol[1];
  int voff0 = srow[0] * SEQ + s * 64 + scol[0];
  int voff1 = srow[1] * SEQ + s * 64 + scol[1];

  s8v aq[4];
#pragma unroll
  for (int kc = 0; kc < 4; kc++)
    aq[kc] = *reinterpret_cast<const s8v*>(
        &Qb[(q0w + l31) * DM + head * HD + kc * 16 + lh * 8]);

  const int x7 = l31 & 7;
  const int rbase = l31 * 128;

  f32x16 minit;                       // loop-invariant C-init for QK MFMA
#pragma unroll
  for (int r = 0; r < 16; r++) minit[r] = -FOFF;

  f32x16 O0 = {}, O1 = {};   // O^T[d][q]: d = db*32 + (r&3)+8*(r>>2)+4*lh, q = l31
  float lsum = 0.f;

  if (s < ntiles) {
    gload16(Kh + koff0, (char*)Ks[0] + ldsoff0);
    gload16(Kh + koff1, (char*)Ks[0] + ldsoff1);
    gload16(Vh + voff0, (char*)Vs[0] + ldsoff0);
    gload16(Vh + voff1, (char*)Vs[0] + ldsoff1);
    __asm__ volatile("s_waitcnt vmcnt(0)" ::: "memory");
  }
  __syncthreads();
  koff0 += 256 * DM; koff1 += 256 * DM;
  voff0 += 256;      voff1 += 256;

  for (int t = s; t < ntiles; t += 4) {
    const int cur = ((t - s) >> 2) & 1;
    if (t + 4 < ntiles) {
      const int nxt = cur ^ 1;
      gload16(Kh + koff0, (char*)Ks[nxt] + ldsoff0);
      gload16(Kh + koff1, (char*)Ks[nxt] + ldsoff1);
      gload16(Vh + voff0, (char*)Vs[nxt] + ldsoff0);
      gload16(Vh + voff1, (char*)Vs[nxt] + ldsoff1);
    }
    koff0 += 256 * DM; koff1 += 256 * DM;
    voff0 += 256;      voff1 += 256;
    const int kb = t * 64;
    if (kb <= q0w + 31) {
      const char* const kbuf = (const char*)Ks[cur];
      const char* const vbuf = (const char*)Vs[cur];
      // ---- swapped QK^T: S^T[key][q]; first MFMA consumes minit as C ----
      f32x16 z0, z1;
      {
        const int so = (lh ^ x7) << 4;   // kc = 0
        const s8v k0 = *reinterpret_cast<const s8v*>(kbuf + rbase + so);
        const s8v k1 = *reinterpret_cast<const s8v*>(kbuf + 4096 + rbase + so);
        z0 = __builtin_amdgcn_mfma_f32_32x32x16_bf16(k0, aq[0], minit, 0, 0, 0);
        z1 = __builtin_amdgcn_mfma_f32_32x32x16_bf16(k1, aq[0], minit, 0, 0, 0);
      }
#pragma unroll
      for (int kc = 1; kc < 4; kc++) {
        const int so = ((kc * 2 + lh) ^ x7) << 4;
        const s8v k0 = *reinterpret_cast<const s8v*>(kbuf + rbase + so);
        const s8v k1 = *reinterpret_cast<const s8v*>(kbuf + 4096 + rbase + so);
        z0 = __builtin_amdgcn_mfma_f32_32x32x16_bf16(k0, aq[kc], z0, 0, 0, 0);
        z1 = __builtin_amdgcn_mfma_f32_32x32x16_bf16(k1, aq[kc], z1, 0, 0, 0);
      }
      if (kb + 63 > q0w) {
        const int qm = q0w + l31 - kb - 4 * lh;   // mask if koff > qm
#pragma unroll
        for (int r = 0; r < 16; r++) {
          const int koff = (r & 3) + 8 * (r >> 2);
          z0[r] = (koff > qm) ? -1e30f : z0[r];
          z1[r] = (koff + 32 > qm) ? -1e30f : z1[r];
        }
      }
      f32x2 sa = {0.f, 0.f}, sb = {0.f, 0.f};
#pragma unroll
      for (int r = 0; r < 8; r++) {
        z0[2 * r] = exp2f(z0[2 * r]);
        z0[2 * r + 1] = exp2f(z0[2 * r + 1]);
        f32x2 e0; e0[0] = z0[2 * r]; e0[1] = z0[2 * r + 1];
        sa += e0;
        z1[2 * r] = exp2f(z1[2 * r]);
        z1[2 * r + 1] = exp2f(z1[2 * r + 1]);
        f32x2 e1; e1[0] = z1[2 * r]; e1[1] = z1[2 * r + 1];
        sb += e1;
      }
      sa += sb;
      lsum += sa[0] + sa[1];
      s8v pf[4];
#define PACKKC(V, base, dst)                                                 \
      {                                                                      \
        unsigned int A0 = cvtpk(V[base + 0], V[base + 1]);                   \
        unsigned int B0 = cvtpk(V[base + 2], V[base + 3]);                   \
        unsigned int A1 = cvtpk(V[base + 4], V[base + 5]);                   \
        unsigned int B1 = cvtpk(V[base + 6], V[base + 7]);                   \
        asm("v_permlane32_swap_b32 %0, %1" : "+v"(A0), "+v"(A1));            \
        asm("v_permlane32_swap_b32 %0, %1" : "+v"(B0), "+v"(B1));            \
        u32x4 q_ = {A0, B0, A1, B1};                                         \
        dst = __builtin_bit_cast(s8v, q_);                                   \
      }
      PACKKC(z0, 0, pf[0]);
      PACKKC(z0, 8, pf[1]);
      PACKKC(z1, 0, pf[2]);
      PACKKC(z1, 8, pf[3]);
#undef PACKKC
#pragma unroll
      for (int kc = 0; kc < 4; kc++) {
        const int so = ((kc * 2 + lh) ^ x7) << 4;
        const s8v v0 = *reinterpret_cast<const s8v*>(vbuf + rbase + so);
        const s8v v1 = *reinterpret_cast<const s8v*>(vbuf + 4096 + rbase + so);
        O0 = __builtin_amdgcn_mfma_f32_32x32x16_bf16(v0, pf[kc], O0, 0, 0, 0);
        O1 = __builtin_amdgcn_mfma_f32_32x32x16_bf16(v1, pf[kc], O1, 0, 0, 0);
      }
    }
    __asm__ volatile("s_waitcnt vmcnt(0)" ::: "memory");
    __syncthreads();
  }

  lsum += __shfl_xor(lsum, 32);
  _Float16* const op = Opart + (size_t)s * SEQ * DM + (size_t)(q0w + l31) * DM +
                       head * HD + 4 * lh;
#pragma unroll
  for (int k = 0; k < 4; k++) {
    h16x4 o0h, o1h;
#pragma unroll
    for (int r = 0; r < 4; r++) {
      o0h[r] = (_Float16)O0[k * 4 + r];
      o1h[r] = (_Float16)O1[k * 4 + r];
    }
    *reinterpret_cast<h16x4*>(op + 8 * k) = o0h;        // d = 8k + 4lh + r
    *reinterpret_cast<h16x4*>(op + 32 + 8 * k) = o1h;   // d = 32 + 8k + 4lh + r
  }
  if (lh == 0)
    lw[(s * NH + head) * SEQ + q0w + l31] = lsum;
}

// ---------------- merge the 4 key-split partials (plain sums) -> bf16 attn ----------------
__global__ __launch_bounds__(256) void k_merge(const _Float16* __restrict__ Opart,
                                               const float* __restrict__ lw,
                                               unsigned short* __restrict__ attn) {
  const int idx = blockIdx.x * 256 + threadIdx.x;
  const int e4 = idx * 4;                   // 4 consecutive d-elements
  const int row = e4 / DM;
  const int col = e4 - row * DM;
  const int head = col >> 6;
  const float l0 = lw[(0 * NH + head) * SEQ + row];
  const float l1 = lw[(1 * NH + head) * SEQ + row];
  const float l2 = lw[(2 * NH + head) * SEQ + row];
  const float l3 = lw[(3 * NH + head) * SEQ + row];
  const float rl = 1.f / (l0 + l1 + l2 + l3);
  const size_t SD = (size_t)SEQ * DM;
  const h16x4 o0 = *reinterpret_cast<const h16x4*>(Opart + e4);
  const h16x4 o1 = *reinterpret_cast<const h16x4*>(Opart + SD + e4);
  const h16x4 o2 = *reinterpret_cast<const h16x4*>(Opart + 2 * SD + e4);
  const h16x4 o3 = *reinterpret_cast<const h16x4*>(Opart + 3 * SD + e4);
  u16x4 pk;
#pragma unroll
  for (int j = 0; j < 4; j++)
    pk[j] = f2bf(((float)o0[j] + (float)o1[j] + (float)o2[j] + (float)o3[j]) * rl);
  *reinterpret_cast<u16x4*>(attn + e4) = pk;
}

extern "C" void kernel_launch(void* const* d_in, const int* in_sizes, int n_in,
                              void* d_out, int out_size, void* d_ws, size_t ws_size,
                              hipStream_t stream) {
  (void)in_sizes; (void)n_in; (void)out_size; (void)ws_size;
  const float* tokens = (const float*)d_in[0];
  const float* wqkv  = (const float*)d_in[2];
  const float* bqkv  = (const float*)d_in[3];
  const float* wproj = (const float*)d_in[4];
  const float* bproj = (const float*)d_in[5];
  float* out = (float*)d_out;

  unsigned short* tok    = (unsigned short*)d_ws;       // [4096][768]
  unsigned short* wqkvT  = tok + 4096 * 768;            // [2304][768]
  unsigned short* wprojT = wqkvT + 2304 * 768;          // [768][768]
  unsigned short* Qb     = wprojT + 768 * 768;          // [4096][768] (pre-scaled)
  unsigned short* Kb     = Qb + 4096 * 768;             // [4096][768]
  unsigned short* Vt     = Kb + 4096 * 768;             // [768][4096]
  unsigned short* attn   = Vt + 768 * 4096;             // [4096][768]
  _Float16* Opart = (_Float16*)(attn + 4096 * 768);     // 4 x [4096][768] f16
  float* lw = (float*)(Opart + 4 * (size_t)4096 * 768); // 4 x 12 x 4096 f32

  k_prep<<<5376, 256, 0, stream>>>(tokens, wqkv, wproj, tok, wqkvT, wprojT);
  k_gemm<128, 64, 0><<<dim3(32, 36), 256, 0, stream>>>(tok, wqkvT, bqkv, Qb, Kb, Vt, nullptr);
  k_attn<<<1536, 256, 0, stream>>>(Qb, Kb, Vt, Opart, lw);
  k_merge<<<3072, 256, 0, stream>>>(Opart, lw, attn);
  k_gemm<64, 64, 1><<<dim3(64, 12), 256, 0, stream>>>(attn, wprojT, bproj, nullptr, nullptr, nullptr, out);
}